// Round 7
// baseline (207.410 us; speedup 1.0000x reference)
//
#include <hip/hip_runtime.h>

#define Nn 4096
#define FIN 512
#define NH 8
#define O1 512
#define LOG2E 1.44269504088896f

typedef __attribute__((ext_vector_type(8))) short short8;
typedef __attribute__((ext_vector_type(4))) float f32x4;
typedef __attribute__((ext_vector_type(2))) unsigned int u32x2;

__device__ __forceinline__ unsigned short f2bf(float f){
  union{float f; unsigned u;} x; x.f=f;
  unsigned r = x.u + 0x7fffu + ((x.u>>16)&1u);
  return (unsigned short)(r>>16);
}
__device__ __forceinline__ float bf2f(unsigned short b){
  union{unsigned u; float f;} x; x.u=((unsigned)b)<<16;
  return x.f;
}
// packed f32x2 -> bf16x2 (RNE), single instruction
__device__ __forceinline__ unsigned cvtpk_bf16(float a, float b){
  unsigned r; asm("v_cvt_pk_bf16_f32 %0, %1, %2" : "=v"(r) : "v"(a), "v"(b));
  return r;
}

// ---- pack adjacency int32 -> bitmask (one uint64 per 64 cols) ----
__global__ void k_pack_adj(const int* __restrict__ adj, unsigned long long* __restrict__ adjw){
  size_t tid = (size_t)blockIdx.x*blockDim.x + threadIdx.x;
  int v = __builtin_nontemporal_load(adj + tid);
  unsigned long long m = __ballot(v>0);
  if((threadIdx.x&63)==0) adjw[tid>>6] = m;
}

// ---- f32 -> bf16 convert ----
__global__ void k_cvt(const float* __restrict__ in, unsigned short* __restrict__ out, int n){
  int i = (blockIdx.x*blockDim.x + threadIdx.x)*4;
  if(i>=n) return;
  float4 v = *(const float4*)(in+i);
  u32x2 pk; pk.x = cvtpk_bf16(v.x, v.y); pk.y = cvtpk_bf16(v.z, v.w);
  *(u32x2*)(out+i) = pk;
}

// ---- K-split GEMM: C^T[o][m] = sum_k A[m][k]*B[o][k] ----
template<int NWC, int KS>
__global__ __launch_bounds__(NWC*KS*64, 2)
void k_gemm3(const unsigned short* __restrict__ A, const unsigned short* __restrict__ B,
             unsigned short* __restrict__ CT, int M, int K, int O){
  int t=threadIdx.x, l=t&63, w=t>>6;
  int wc=w%NWC, ks=w/NWC;
  int m0=blockIdx.x*32, o0=blockIdx.y*(NWC*32);
  int row=l&15, kq=(l>>4)*8, g=l>>4;
  int kw=K/KS;
  const unsigned short* Ab = A + (size_t)(m0+row)*K + ks*kw + kq;
  const unsigned short* Bb = B + (size_t)(o0+wc*32+row)*K + ks*kw + kq;
  f32x4 acc[2][2]={};
  #pragma unroll 2
  for(int k0=0;k0<kw;k0+=32){
    short8 a0=*(const short8*)(Ab+k0);
    short8 a1=*(const short8*)(Ab+(size_t)16*K+k0);
    short8 b0=*(const short8*)(Bb+k0);
    short8 b1=*(const short8*)(Bb+(size_t)16*K+k0);
    acc[0][0]=__builtin_amdgcn_mfma_f32_16x16x32_bf16(a0,b0,acc[0][0],0,0,0);
    acc[0][1]=__builtin_amdgcn_mfma_f32_16x16x32_bf16(a0,b1,acc[0][1],0,0,0);
    acc[1][0]=__builtin_amdgcn_mfma_f32_16x16x32_bf16(a1,b0,acc[1][0],0,0,0);
    acc[1][1]=__builtin_amdgcn_mfma_f32_16x16x32_bf16(a1,b1,acc[1][1],0,0,0);
  }
  // col = oi*18 + row: disjoint ranges (0..15 / 18..33), 2-way bank alias = free
  __shared__ float red[NWC][KS/2][32][36];
  for(int s=KS/2;s>=1;s>>=1){
    if(ks>=s && ks<2*s){
      #pragma unroll
      for(int mi=0;mi<2;mi++)
      #pragma unroll
      for(int oi=0;oi<2;oi++)
      #pragma unroll
      for(int r=0;r<4;r++)
        red[wc][ks-s][mi*16+g*4+r][oi*18+row]=acc[mi][oi][r];
    }
    __syncthreads();
    if(ks<s){
      #pragma unroll
      for(int mi=0;mi<2;mi++)
      #pragma unroll
      for(int oi=0;oi<2;oi++)
      #pragma unroll
      for(int r=0;r<4;r++)
        acc[mi][oi][r]+=red[wc][ks][mi*16+g*4+r][oi*18+row];
    }
    __syncthreads();
  }
  if(ks==0){
    #pragma unroll
    for(int mi=0;mi<2;mi++)
    #pragma unroll
    for(int oi=0;oi<2;oi++){
      int m=m0+mi*16+g*4;
      int o=o0+wc*32+oi*16+row;
      u32x2 pk;
      pk.x=cvtpk_bf16(acc[mi][oi][0], acc[mi][oi][1]);
      pk.y=cvtpk_bf16(acc[mi][oi][2], acc[mi][oi][3]);
      __builtin_nontemporal_store(pk, (u32x2*)&CT[(size_t)o*M+m]);
    }
  }
}

// ---- per-node score factors ----
// s1 = (wh @ a1)*log2e, s2 = (wh @ a2)*log2e.
// exp2(LeakyReLU(s1+s2)) = max(2^s1*2^s2, 2^(.2 s1)*2^(.2 s2))
// so store E=2^s, F=2^(0.2 s) per node.
__global__ void k_wh12(const unsigned short* __restrict__ whT,
                       const float* __restrict__ a1, const float* __restrict__ a2,
                       float2* __restrict__ e1f1, float2* __restrict__ e2f2){
  const int M=Nn;
  int n=blockIdx.x*blockDim.x+threadIdx.x;
  int h=blockIdx.y;
  float s1=0.f,s2=0.f;
  for(int c=0;c<64;c++){
    float v=bf2f(whT[(size_t)(h*64+c)*M+n]);
    s1+=v*a1[h*64+c];
    s2+=v*a2[h*64+c];
  }
  float s1L=s1*LOG2E, s2L=s2*LOG2E;
  float2 r1; r1.x=__builtin_amdgcn_exp2f(s1L); r1.y=__builtin_amdgcn_exp2f(0.2f*s1L);
  float2 r2; r2.x=__builtin_amdgcn_exp2f(s2L); r2.y=__builtin_amdgcn_exp2f(0.2f*s2L);
  e1f1[(size_t)h*M+n]=r1;
  e2f2[(size_t)h*M+n]=r2;
}

// ---- barrier-free fused attention, factorized scores ----
// p_ij = adj_ij ? max(E1_i*E2_j, F1_i*F2_j) : 0   (no exp in inner loop)
template<int FINAL, int NJS, int RF, int LOGH>
__global__ __launch_bounds__(NJS*64, 4)
void k_attn4(const unsigned long long* __restrict__ adjw,
             const float2* __restrict__ e1f1, const float2* __restrict__ e2f2,
             const unsigned short* __restrict__ whT,
             unsigned short* __restrict__ Hmat, float* __restrict__ outF){
  const int M = Nn;
  int t = threadIdx.x, l = t & 63, js = t >> 6;
  int lr = l & 15, g = l >> 4;
  int bid = blockIdx.x;
  int h = bid & ((1<<LOGH)-1);        // head in low bits -> pinned per XCD
  int bx = bid >> LOGH;
  int i_base = bx * (RF*16);
  const float2* ef2h = e2f2 + (size_t)h * M;
  const unsigned short* Vb = whT + (size_t)h * 64 * M;

  float E1[RF], F1[RF];
  const unsigned long long* arow[RF];
  #pragma unroll
  for (int rf = 0; rf < RF; rf++) {
    int i = i_base + rf*16 + lr;
    float2 ef = e1f1[(size_t)h*M + i];
    E1[rf] = ef.x; F1[rf] = ef.y;
    arow[rf] = adjw + (size_t)i * 64;
  }
  short8 ones;
  #pragma unroll
  for (int q=0;q<8;q++) ones[q] = (short)0x3F80;   // bf16 1.0

  f32x4 acc[RF][4] = {};
  f32x4 accd[RF] = {};
  const int chunk = Nn / NJS;
  const int jlo = js * chunk;

  #pragma unroll 2
  for (int j0 = jlo; j0 < jlo + chunk; j0 += 64) {
    unsigned long long wrd[RF];
    #pragma unroll
    for (int rf=0; rf<RF; rf++)
      wrd[rf] = __builtin_nontemporal_load(arow[rf] + (j0 >> 6));
    #pragma unroll
    for (int half = 0; half < 2; half++) {
      int j = j0 + half*32 + g*8;
      const float2* efp = ef2h + j;
      float4 c0 = *(const float4*)(efp+0);
      float4 c1 = *(const float4*)(efp+2);
      float4 c2 = *(const float4*)(efp+4);
      float4 c3 = *(const float4*)(efp+6);
      float Ee[8] = {c0.x,c0.z,c1.x,c1.z,c2.x,c2.z,c3.x,c3.z};
      float Ff[8] = {c0.y,c0.w,c1.y,c1.w,c2.y,c2.w,c3.y,c3.w};
      short8 bfr[4];
      #pragma unroll
      for (int ct = 0; ct < 4; ct++)
        bfr[ct] = *(const short8*)(Vb + (size_t)(ct*16 + lr) * M + j);
      #pragma unroll
      for (int rf = 0; rf < RF; rf++) {
        unsigned bits = (unsigned)(wrd[rf] >> (half*32 + g*8)) & 0xffu;
        float pf[8];
        #pragma unroll
        for (int q = 0; q < 8; q++) {
          float m = E1[rf]*Ee[q];
          float f = F1[rf]*Ff[q];
          float p = fmaxf(m, f);                 // = exp2(LeakyReLU(s))
          int mk = (int)(bits << (31-q)) >> 31;  // -1 if edge present else 0
          pf[q] = __uint_as_float(__float_as_uint(p) & (unsigned)mk);
        }
        union { unsigned u[4]; short8 v; } pu;
        #pragma unroll
        for (int k = 0; k < 4; k++) pu.u[k] = cvtpk_bf16(pf[2*k], pf[2*k+1]);
        #pragma unroll
        for (int ct = 0; ct < 4; ct++)
          acc[rf][ct] = __builtin_amdgcn_mfma_f32_16x16x32_bf16(pu.v, bfr[ct], acc[rf][ct], 0,0,0);
        accd[rf] = __builtin_amdgcn_mfma_f32_16x16x32_bf16(pu.v, ones, accd[rf], 0,0,0);
      }
    }
  }

  // ---- cross-wave j-split combine (stride 68 -> exact 2-way banks = free) ----
  constexpr int NS = NJS/2;
  __shared__ float redA[NS][RF*16][68];
  __shared__ float redD[NS][RF*16];
  for (int s = NJS/2; s >= 1; s >>= 1) {
    if (js >= s && js < 2*s) {
      #pragma unroll
      for (int rf=0; rf<RF; rf++) {
        #pragma unroll
        for (int ct=0; ct<4; ct++)
          #pragma unroll
          for (int r=0; r<4; r++)
            redA[js-s][rf*16+g*4+r][ct*16+lr] = acc[rf][ct][r];
        if (lr == 0) {
          #pragma unroll
          for (int r=0; r<4; r++)
            redD[js-s][rf*16+g*4+r] = accd[rf][r];
        }
      }
    }
    __syncthreads();
    if (js < s) {
      #pragma unroll
      for (int rf=0; rf<RF; rf++) {
        #pragma unroll
        for (int ct=0; ct<4; ct++)
          #pragma unroll
          for (int r=0; r<4; r++)
            acc[rf][ct][r] += redA[js][rf*16+g*4+r][ct*16+lr];
        #pragma unroll
        for (int r=0; r<4; r++)
          accd[rf][r] += redD[js][rf*16+g*4+r];
      }
    }
    __syncthreads();
  }

  // ---- epilogue: normalize, ELU, (log_softmax) ----
  if (js == 0) {
    #pragma unroll
    for (int rf=0; rf<RF; rf++) {
      float vv[4][4];
      #pragma unroll
      for (int r=0; r<4; r++) {
        float d  = fmaxf(accd[rf][r], 1e-30f);
        float rd = 1.f/d;
        #pragma unroll
        for (int ct=0; ct<4; ct++) {
          float v = acc[rf][ct][r] * rd;
          vv[ct][r] = v > 0.f ? v : __expf(v) - 1.f;  // ELU
        }
      }
      if (FINAL) {
        #pragma unroll
        for (int r=0; r<4; r++) {
          float m = fmaxf(fmaxf(vv[0][r],vv[1][r]), fmaxf(vv[2][r],vv[3][r]));
          #pragma unroll
          for (int dd=1; dd<16; dd<<=1) m = fmaxf(m, __shfl_xor(m, dd));
          float sEx = 0.f;
          #pragma unroll
          for (int ct=0; ct<4; ct++) sEx += __expf(vv[ct][r] - m);
          #pragma unroll
          for (int dd=1; dd<16; dd<<=1) sEx += __shfl_xor(sEx, dd);
          float lg = m + __logf(sEx);
          int row = i_base + g*4 + r;
          #pragma unroll
          for (int ct=0; ct<4; ct++)
            __builtin_nontemporal_store(vv[ct][r]-lg, &outF[(size_t)row*64 + ct*16 + lr]);
        }
      } else {
        #pragma unroll
        for (int r=0; r<4; r++) {
          int row = i_base + rf*16 + g*4 + r;
          #pragma unroll
          for (int ct=0; ct<4; ct++)
            __builtin_nontemporal_store(f2bf(vv[ct][r]),
                &Hmat[(size_t)row*O1 + h*64 + ct*16 + lr]);
        }
      }
    }
  }
}

extern "C" void kernel_launch(void* const* d_in, const int* in_sizes, int n_in,
                              void* d_out, int out_size, void* d_ws, size_t ws_size,
                              hipStream_t stream){
  const float* x  = (const float*)d_in[0];
  const int* adj  = (const int*)d_in[1];
  const float* W  = (const float*)d_in[2];
  const float* a1 = (const float*)d_in[3];
  const float* a2 = (const float*)d_in[4];
  const float* W2 = (const float*)d_in[5];
  const float* a21= (const float*)d_in[6];
  const float* a22= (const float*)d_in[7];
  float* out = (float*)d_out;
  char* ws = (char*)d_ws;

  size_t off=0;
  unsigned long long* adjw = (unsigned long long*)(ws+off); off += (size_t)Nn*64*8;
  unsigned short* xb   = (unsigned short*)(ws+off); off += (size_t)Nn*FIN*2;
  unsigned short* Wb   = (unsigned short*)(ws+off); off += (size_t)O1*FIN*2;
  unsigned short* W2b  = (unsigned short*)(ws+off); off += (size_t)64*FIN*2;
  unsigned short* whT1 = (unsigned short*)(ws+off); off += (size_t)O1*Nn*2;
  unsigned short* Hmat = (unsigned short*)(ws+off); off += (size_t)Nn*O1*2;
  unsigned short* whT2 = (unsigned short*)(ws+off); off += (size_t)64*Nn*2;
  float2* e1f1a = (float2*)(ws+off); off += (size_t)NH*Nn*8;
  float2* e2f2a = (float2*)(ws+off); off += (size_t)NH*Nn*8;
  float2* e1f1b = (float2*)(ws+off); off += (size_t)Nn*8;
  float2* e2f2b = (float2*)(ws+off); off += (size_t)Nn*8;

  k_pack_adj<<<(Nn*(size_t)Nn)/256, 256, 0, stream>>>(adj, adjw);
  k_cvt<<<(Nn*FIN/4+255)/256, 256, 0, stream>>>(x, xb, Nn*FIN);
  k_cvt<<<(O1*FIN/4+255)/256, 256, 0, stream>>>(W, Wb, O1*FIN);
  k_cvt<<<(64*FIN/4+255)/256, 256, 0, stream>>>(W2, W2b, 64*FIN);
  // layer-1 projection: 32x64 tiles, 4-way K-split
  k_gemm3<2,4><<<dim3(Nn/32, O1/64), 512, 0, stream>>>(xb, Wb, whT1, Nn, FIN, O1);
  k_wh12<<<dim3(Nn/256, NH), 256, 0, stream>>>(whT1, a1, a2, e1f1a, e2f2a);
  // layer-1 attention: 32 rows/block, 8 j-split waves, grid 1024
  k_attn4<0, 8, 2, 3><<<(Nn/32)*NH, 512, 0, stream>>>(adjw, e1f1a, e2f2a, whT1, Hmat, nullptr);
  // layer-2 projection: 8-way K-split
  k_gemm3<2,8><<<dim3(Nn/32, 1), 1024, 0, stream>>>(Hmat, W2b, whT2, Nn, FIN, 64);
  k_wh12<<<dim3(Nn/256, 1), 256, 0, stream>>>(whT2, a21, a22, e1f1b, e2f2b);
  // layer-2 attention: 16 rows/block, 16 j-split waves, grid 256
  k_attn4<1, 16, 1, 0><<<Nn/16, 1024, 0, stream>>>(adjw, e1f1b, e2f2b, whT2, nullptr, out);
  (void)in_sizes; (void)n_in; (void)out_size; (void)ws_size;
}

// Round 8
// 160.094 us; speedup vs baseline: 1.2956x; 1.2956x over previous
//
#include <hip/hip_runtime.h>

#define Nn 4096
#define FIN 512
#define NH 8
#define O1 512
#define LOG2E 1.44269504088896f

typedef __attribute__((ext_vector_type(8))) short short8;
typedef __attribute__((ext_vector_type(4))) float f32x4;
typedef __attribute__((ext_vector_type(2))) unsigned int u32x2;

__device__ __forceinline__ unsigned short f2bf(float f){
  union{float f; unsigned u;} x; x.f=f;
  unsigned r = x.u + 0x7fffu + ((x.u>>16)&1u);
  return (unsigned short)(r>>16);
}
__device__ __forceinline__ float bf2f(unsigned short b){
  union{unsigned u; float f;} x; x.u=((unsigned)b)<<16;
  return x.f;
}
__device__ __forceinline__ unsigned cvtpk_bf16(float a, float b){
  unsigned r; asm("v_cvt_pk_bf16_f32 %0, %1, %2" : "=v"(r) : "v"(a), "v"(b));
  return r;
}

// ---- pack adjacency int32 -> bitmask ----
__global__ void k_pack_adj(const int* __restrict__ adj, unsigned long long* __restrict__ adjw){
  size_t tid = (size_t)blockIdx.x*blockDim.x + threadIdx.x;
  int v = __builtin_nontemporal_load(adj + tid);   // 64MB read-once
  unsigned long long m = __ballot(v>0);
  if((threadIdx.x&63)==0) adjw[tid>>6] = m;
}

// ---- f32 -> bf16 convert ----
__global__ void k_cvt(const float* __restrict__ in, unsigned short* __restrict__ out, int n){
  int i = (blockIdx.x*blockDim.x + threadIdx.x)*4;
  if(i>=n) return;
  float4 v = *(const float4*)(in+i);
  u32x2 pk; pk.x = cvtpk_bf16(v.x, v.y); pk.y = cvtpk_bf16(v.z, v.w);
  *(u32x2*)(out+i) = pk;
}

// ---- K-split GEMM: C^T[o][m] = sum_k A[m][k]*B[o][k] (plain cached stores) ----
template<int NWC, int KS>
__global__ __launch_bounds__(NWC*KS*64, 2)
void k_gemm3(const unsigned short* __restrict__ A, const unsigned short* __restrict__ B,
             unsigned short* __restrict__ CT, int M, int K, int O){
  int t=threadIdx.x, l=t&63, w=t>>6;
  int wc=w%NWC, ks=w/NWC;
  int m0=blockIdx.x*32, o0=blockIdx.y*(NWC*32);
  int row=l&15, kq=(l>>4)*8, g=l>>4;
  int kw=K/KS;
  const unsigned short* Ab = A + (size_t)(m0+row)*K + ks*kw + kq;
  const unsigned short* Bb = B + (size_t)(o0+wc*32+row)*K + ks*kw + kq;
  f32x4 acc[2][2]={};
  #pragma unroll 2
  for(int k0=0;k0<kw;k0+=32){
    short8 a0=*(const short8*)(Ab+k0);
    short8 a1=*(const short8*)(Ab+(size_t)16*K+k0);
    short8 b0=*(const short8*)(Bb+k0);
    short8 b1=*(const short8*)(Bb+(size_t)16*K+k0);
    acc[0][0]=__builtin_amdgcn_mfma_f32_16x16x32_bf16(a0,b0,acc[0][0],0,0,0);
    acc[0][1]=__builtin_amdgcn_mfma_f32_16x16x32_bf16(a0,b1,acc[0][1],0,0,0);
    acc[1][0]=__builtin_amdgcn_mfma_f32_16x16x32_bf16(a1,b0,acc[1][0],0,0,0);
    acc[1][1]=__builtin_amdgcn_mfma_f32_16x16x32_bf16(a1,b1,acc[1][1],0,0,0);
  }
  // col = oi*18 + row: disjoint (0..15 / 18..33), 2-way bank alias = free
  __shared__ float red[NWC][KS/2][32][36];
  for(int s=KS/2;s>=1;s>>=1){
    if(ks>=s && ks<2*s){
      #pragma unroll
      for(int mi=0;mi<2;mi++)
      #pragma unroll
      for(int oi=0;oi<2;oi++)
      #pragma unroll
      for(int r=0;r<4;r++)
        red[wc][ks-s][mi*16+g*4+r][oi*18+row]=acc[mi][oi][r];
    }
    __syncthreads();
    if(ks<s){
      #pragma unroll
      for(int mi=0;mi<2;mi++)
      #pragma unroll
      for(int oi=0;oi<2;oi++)
      #pragma unroll
      for(int r=0;r<4;r++)
        acc[mi][oi][r]+=red[wc][ks][mi*16+g*4+r][oi*18+row];
    }
    __syncthreads();
  }
  if(ks==0){
    #pragma unroll
    for(int mi=0;mi<2;mi++)
    #pragma unroll
    for(int oi=0;oi<2;oi++){
      int m=m0+mi*16+g*4;
      int o=o0+wc*32+oi*16+row;
      u32x2 pk;
      pk.x=cvtpk_bf16(acc[mi][oi][0], acc[mi][oi][1]);
      pk.y=cvtpk_bf16(acc[mi][oi][2], acc[mi][oi][3]);
      *(u32x2*)&CT[(size_t)o*M+m] = pk;   // plain store: CT is re-read a lot
    }
  }
}

// ---- per-node score factors: E=2^(s*log2e), F=2^(0.2*s*log2e) ----
__global__ void k_wh12(const unsigned short* __restrict__ whT,
                       const float* __restrict__ a1, const float* __restrict__ a2,
                       float2* __restrict__ e1f1, float2* __restrict__ e2f2){
  const int M=Nn;
  int n=blockIdx.x*blockDim.x+threadIdx.x;
  int h=blockIdx.y;
  float s1=0.f,s2=0.f;
  for(int c=0;c<64;c++){
    float v=bf2f(whT[(size_t)(h*64+c)*M+n]);
    s1+=v*a1[h*64+c];
    s2+=v*a2[h*64+c];
  }
  float s1L=s1*LOG2E, s2L=s2*LOG2E;
  float2 r1; r1.x=__builtin_amdgcn_exp2f(s1L); r1.y=__builtin_amdgcn_exp2f(0.2f*s1L);
  float2 r2; r2.x=__builtin_amdgcn_exp2f(s2L); r2.y=__builtin_amdgcn_exp2f(0.2f*s2L);
  e1f1[(size_t)h*M+n]=r1;
  e2f2[(size_t)h*M+n]=r2;
}

// ---- fused attention, LDS-staged V, row-split waves ----
// Block: 4 waves x 16 rows = 64 rows. V tile [64][64] double-buffered in LDS
// ([64][72] padded, reg-staged, issue-early/write-late). One barrier/step.
// FINAL=0: full-j sweep, direct epilogue -> Hmat.  FINAL=1: j-chunked (8),
// fp32 partials -> k_fin.
template<int FINAL, int JSTEPS, int LOGH>
__global__ __launch_bounds__(256, 2)
void k_attn5(const unsigned long long* __restrict__ adjw,
             const float2* __restrict__ e1f1, const float2* __restrict__ e2f2,
             const unsigned short* __restrict__ whT,
             unsigned short* __restrict__ Hmat,
             float* __restrict__ Opart, float* __restrict__ Dpart){
  const int M = Nn;
  __shared__ unsigned short buf[2][64][72];
  int t = threadIdx.x, l = t & 63, w = t >> 6;
  int lr = l & 15, g = l >> 4;
  int bid = blockIdx.x;
  int h = bid & ((1<<LOGH)-1);
  int bx = bid >> LOGH;
  int rowtile, jc;
  if (FINAL) { jc = bx & 7; rowtile = bx >> 3; }
  else       { jc = 0;      rowtile = bx; }
  int i_base = rowtile*64;
  int jbase = jc * (JSTEPS*64);
  const float2* ef2h = e2f2 + (size_t)h*M;
  const unsigned short* Vb = whT + (size_t)h*64*M;
  int i = i_base + w*16 + lr;
  float2 ef = e1f1[(size_t)h*M + i];
  float E1 = ef.x, F1 = ef.y;
  const unsigned long long* arow = adjw + (size_t)i*64;

  // staging: thread t owns (row = t>>2, cols [spos0*8, spos0*8+16))
  int srow = t >> 2;
  int spos0 = (t & 3)*2;
  const unsigned short* vsrc = Vb + (size_t)srow*M + jbase + spos0*8;

  short8 ones;
  #pragma unroll
  for (int q=0;q<8;q++) ones[q] = (short)0x3F80;

  f32x4 acc[4] = {};
  f32x4 accd = {};

  // prologue: stage step 0
  short8 ra = *(const short8*)(vsrc);
  short8 rb = *(const short8*)(vsrc + 8);
  *(short8*)&buf[0][srow][spos0*8]   = ra;
  *(short8*)&buf[0][srow][spos0*8+8] = rb;

  for (int s = 0; s < JSTEPS; s++){
    int j0 = jbase + s*64;
    if (s+1 < JSTEPS){                    // issue next-tile loads early
      ra = *(const short8*)(vsrc + (s+1)*64);
      rb = *(const short8*)(vsrc + (s+1)*64 + 8);
    }
    unsigned long long wrd = arow[j0>>6];
    unsigned puh[2][4];
    #pragma unroll
    for (int half = 0; half < 2; half++){
      int j = j0 + half*32 + g*8;
      const float2* efp = ef2h + j;
      float4 c0 = *(const float4*)(efp+0);
      float4 c1 = *(const float4*)(efp+2);
      float4 c2 = *(const float4*)(efp+4);
      float4 c3 = *(const float4*)(efp+6);
      float Ee[8] = {c0.x,c0.z,c1.x,c1.z,c2.x,c2.z,c3.x,c3.z};
      float Ff[8] = {c0.y,c0.w,c1.y,c1.w,c2.y,c2.w,c3.y,c3.w};
      unsigned bits = (unsigned)(wrd >> (half*32 + g*8)) & 0xffu;
      float pf[8];
      #pragma unroll
      for (int q = 0; q < 8; q++){
        float m = E1*Ee[q];
        float f = F1*Ff[q];
        float p = fmaxf(m, f);                 // = exp2(LeakyReLU(s))
        int mk = (int)(bits << (31-q)) >> 31;
        pf[q] = __uint_as_float(__float_as_uint(p) & (unsigned)mk);
      }
      #pragma unroll
      for (int k = 0; k < 4; k++) puh[half][k] = cvtpk_bf16(pf[2*k], pf[2*k+1]);
    }
    __syncthreads();                       // buf[s&1] staged & prev reads done
    #pragma unroll
    for (int half = 0; half < 2; half++){
      union { unsigned u[4]; short8 v; } pu;
      #pragma unroll
      for (int k = 0; k < 4; k++) pu.u[k] = puh[half][k];
      #pragma unroll
      for (int ct = 0; ct < 4; ct++){
        short8 bfr = *(const short8*)&buf[s&1][ct*16+lr][half*32+g*8];
        acc[ct] = __builtin_amdgcn_mfma_f32_16x16x32_bf16(pu.v, bfr, acc[ct], 0,0,0);
      }
      accd = __builtin_amdgcn_mfma_f32_16x16x32_bf16(pu.v, ones, accd, 0,0,0);
    }
    if (s+1 < JSTEPS){                     // write-late into the other buffer
      *(short8*)&buf[(s+1)&1][srow][spos0*8]   = ra;
      *(short8*)&buf[(s+1)&1][srow][spos0*8+8] = rb;
    }
  }

  // ---- epilogue (per-wave, no cross-wave combine) ----
  if (FINAL){
    #pragma unroll
    for (int r=0; r<4; r++){
      int row = i_base + w*16 + g*4 + r;
      if (lr == 0) Dpart[(size_t)jc*Nn + row] = accd[r];
      #pragma unroll
      for (int ct=0; ct<4; ct++)
        Opart[((size_t)jc*Nn + row)*64 + ct*16 + lr] = acc[ct][r];
    }
  } else {
    #pragma unroll
    for (int r=0; r<4; r++){
      float d  = fmaxf(accd[r], 1e-30f);
      float rd = 1.f/d;
      int row = i_base + w*16 + g*4 + r;
      #pragma unroll
      for (int ct=0; ct<4; ct++){
        float v = acc[ct][r]*rd;
        v = v > 0.f ? v : __expf(v) - 1.f;   // ELU
        Hmat[(size_t)row*O1 + h*64 + ct*16 + lr] = f2bf(v);
      }
    }
  }
}

// ---- layer-2 finish: combine 8 j-chunk partials, normalize, ELU, log_softmax ----
__global__ void k_fin(const float* __restrict__ Op, const float* __restrict__ Dp,
                      float* __restrict__ out){
  int w = threadIdx.x>>6, l = threadIdx.x&63;
  int row = blockIdx.x*4 + w;
  float o = 0.f, d = 0.f;
  #pragma unroll
  for (int jc=0; jc<8; jc++){
    o += Op[((size_t)jc*Nn + row)*64 + l];
    d += Dp[(size_t)jc*Nn + row];
  }
  float v = o / fmaxf(d, 1e-30f);
  v = v > 0.f ? v : __expf(v) - 1.f;
  float m = v;
  #pragma unroll
  for (int dd=1; dd<64; dd<<=1) m = fmaxf(m, __shfl_xor(m, dd));
  float s = __expf(v - m);
  #pragma unroll
  for (int dd=1; dd<64; dd<<=1) s += __shfl_xor(s, dd);
  out[(size_t)row*64 + l] = v - (m + __logf(s));
}

extern "C" void kernel_launch(void* const* d_in, const int* in_sizes, int n_in,
                              void* d_out, int out_size, void* d_ws, size_t ws_size,
                              hipStream_t stream){
  const float* x  = (const float*)d_in[0];
  const int* adj  = (const int*)d_in[1];
  const float* W  = (const float*)d_in[2];
  const float* a1 = (const float*)d_in[3];
  const float* a2 = (const float*)d_in[4];
  const float* W2 = (const float*)d_in[5];
  const float* a21= (const float*)d_in[6];
  const float* a22= (const float*)d_in[7];
  float* out = (float*)d_out;
  char* ws = (char*)d_ws;

  size_t off=0;
  unsigned long long* adjw = (unsigned long long*)(ws+off); off += (size_t)Nn*64*8;   // 2MB
  size_t off_xb = off;
  unsigned short* xb   = (unsigned short*)(ws+off); off += (size_t)Nn*FIN*2;          // 4MB
  unsigned short* Wb   = (unsigned short*)(ws+off); off += (size_t)O1*FIN*2;          // .5MB
  unsigned short* W2b  = (unsigned short*)(ws+off); off += (size_t)64*FIN*2;          // 64KB
  unsigned short* whT1 = (unsigned short*)(ws+off); off += (size_t)O1*Nn*2;           // 4MB
  unsigned short* Hmat = (unsigned short*)(ws+off); off += (size_t)Nn*O1*2;           // 4MB
  unsigned short* whT2 = (unsigned short*)(ws+off); off += (size_t)64*Nn*2;           // .5MB
  float2* e1f1a = (float2*)(ws+off); off += (size_t)NH*Nn*8;
  float2* e2f2a = (float2*)(ws+off); off += (size_t)NH*Nn*8;
  float2* e1f1b = (float2*)(ws+off); off += (size_t)Nn*8;
  float2* e2f2b = (float2*)(ws+off); off += (size_t)Nn*8;
  // layer-2 partials alias the dead xb/Wb/W2b/whT1 region (8.56MB available)
  float* Opart = (float*)(ws + off_xb);                   // 8MB
  float* Dpart = (float*)(ws + off_xb + (size_t)8*Nn*64*4); // 128KB

  k_pack_adj<<<(Nn*(size_t)Nn)/256, 256, 0, stream>>>(adj, adjw);
  k_cvt<<<(Nn*FIN/4+255)/256, 256, 0, stream>>>(x, xb, Nn*FIN);
  k_cvt<<<(O1*FIN/4+255)/256, 256, 0, stream>>>(W, Wb, O1*FIN);
  k_cvt<<<(64*FIN/4+255)/256, 256, 0, stream>>>(W2, W2b, 64*FIN);
  k_gemm3<2,4><<<dim3(Nn/32, O1/64), 512, 0, stream>>>(xb, Wb, whT1, Nn, FIN, O1);
  k_wh12<<<dim3(Nn/256, NH), 256, 0, stream>>>(whT1, a1, a2, e1f1a, e2f2a);
  // layer-1 attention: 64 rowtiles x 8 heads, 4 waves/block, full-j sweep
  k_attn5<0, 64, 3><<<(Nn/64)*NH, 256, 0, stream>>>(adjw, e1f1a, e2f2a, whT1, Hmat, nullptr, nullptr);
  k_gemm3<2,8><<<dim3(Nn/32, 1), 1024, 0, stream>>>(Hmat, W2b, whT2, Nn, FIN, 64);
  k_wh12<<<dim3(Nn/256, 1), 256, 0, stream>>>(whT2, a21, a22, e1f1b, e2f2b);
  // layer-2 attention: 64 rowtiles x 8 j-chunks -> partials
  k_attn5<1, 8, 0><<<(Nn/64)*8, 256, 0, stream>>>(adjw, e1f1b, e2f2b, whT2, nullptr, Opart, Dpart);
  k_fin<<<Nn/4, 256, 0, stream>>>(Opart, Dpart, out);
  (void)in_sizes; (void)n_in; (void)out_size; (void)ws_size;
}